// Round 1
// baseline (346.614 us; speedup 1.0000x reference)
//
#include <hip/hip_runtime.h>
#include <stdint.h>

#define BB 8
#define CIN 256
#define NSP 16384      // H*W
#define HID 128

typedef __bf16 bfrag __attribute__((ext_vector_type(8)));
typedef float  f32x4 __attribute__((ext_vector_type(4)));

__device__ __forceinline__ unsigned short f2bf(float f) {
  union { float f; unsigned int u; } v; v.f = f;
  unsigned int u = v.u;
  return (unsigned short)((u + 0x7FFFu + ((u >> 16) & 1u)) >> 16);  // RNE
}

// ---------------- pass 1: k/v GEMM (reads x,w fp32) + exp + row-sums + context partials ----------------
// Block: 128-n tile of one batch, 512 threads = 8 waves.
// GEMM: M=256 (k 0..127 = w_qkv rows 128..255, v 128..255 = w_qkv rows 256..383), K=256, N=128.
// q is never computed here: it is folded into Wcomb = Weff @ Wq (see la_wcomb).
// acc[2][8] = 64 regs (was 96 with q) + x-only prefetch -> target <=128 VGPR -> 2 blocks/CU.
__global__ __launch_bounds__(512, 4) void la_fused(const float* __restrict__ x,
                                                   const float* __restrict__ w_qkv,
                                                   float* __restrict__ ctxp,
                                                   float* __restrict__ sums) {
  __shared__ __align__(16) union {
    struct { unsigned short Wt[256][40]; unsigned short Xb[128][40]; } g;     // 30720 B
    struct { unsigned short Lk[64][136]; unsigned short Lv[64][136];
             float Pc[4][1024]; } e;                                          // 51200 B
  } sh;
  const int chunk = blockIdx.x;
  const int n0 = chunk * 128;
  const int b = blockIdx.y;
  const int t = threadIdx.x;
  const int lane = t & 63, wv = t >> 6;
  const int l15 = lane & 15, q = lane >> 4;
  const int cl = t & 31;
  const int n16 = (t >> 5) * 8;
  const float* xp = x + (size_t)b * CIN * NSP + n0;
  const float* wkv = w_qkv + (size_t)128 * CIN;   // k,v rows only
  f32x4 acc[2][8];
#pragma unroll
  for (int i = 0; i < 2; ++i)
#pragma unroll
    for (int j = 0; j < 8; ++j) acc[i][j] = 0.0f;

  // prefetch x tile for kc=0 into registers
  float4 xa0, xa1;
  {
    const float* xr = xp + (size_t)cl * NSP + n16;
    xa0 = *(const float4*)xr;
    xa1 = *(const float4*)(xr + 4);
  }

  for (int kc = 0; kc < 8; ++kc) {
    // ---- x -> LDS transpose from prefetched regs (no wait: loaded last iter) ----
    sh.g.Xb[n16 + 0][cl] = f2bf(xa0.x);
    sh.g.Xb[n16 + 1][cl] = f2bf(xa0.y);
    sh.g.Xb[n16 + 2][cl] = f2bf(xa0.z);
    sh.g.Xb[n16 + 3][cl] = f2bf(xa0.w);
    sh.g.Xb[n16 + 4][cl] = f2bf(xa1.x);
    sh.g.Xb[n16 + 5][cl] = f2bf(xa1.y);
    sh.g.Xb[n16 + 6][cl] = f2bf(xa1.z);
    sh.g.Xb[n16 + 7][cl] = f2bf(xa1.w);
    // ---- stage W (fp32 -> bf16), 256x32 per kc, 2 tasks/thread (L2-resident) ----
#pragma unroll
    for (int i = 0; i < 2; ++i) {
      const int id = t + i * 512;
      const int row = id >> 2, c8 = (id & 3) * 8;
      const float* wr = wkv + (size_t)row * CIN + kc * 32 + c8;
      const float4 wa = *(const float4*)wr;
      const float4 wb4 = *(const float4*)(wr + 4);
      ushort4 p0, p1;
      p0.x = f2bf(wa.x); p0.y = f2bf(wa.y); p0.z = f2bf(wa.z); p0.w = f2bf(wa.w);
      p1.x = f2bf(wb4.x); p1.y = f2bf(wb4.y); p1.z = f2bf(wb4.z); p1.w = f2bf(wb4.w);
      *(ushort4*)&sh.g.Wt[row][c8] = p0;
      *(ushort4*)&sh.g.Wt[row][c8 + 4] = p1;
    }
    __syncthreads();
    // issue next-kc x loads early; they fly under the ds_read+MFMA phase
    if (kc < 7) {
      const float* xr = xp + (size_t)((kc + 1) * 32 + cl) * NSP + n16;
      xa0 = *(const float4*)xr;
      xa1 = *(const float4*)(xr + 4);
    }
    bfrag a0 = *(const bfrag*)&sh.g.Wt[wv * 16 + l15][q * 8];         // k band
    bfrag a1 = *(const bfrag*)&sh.g.Wt[128 + wv * 16 + l15][q * 8];   // v band
#pragma unroll
    for (int ni = 0; ni < 8; ++ni) {
      bfrag bbv = *(const bfrag*)&sh.g.Xb[ni * 16 + l15][q * 8];
      acc[0][ni] = __builtin_amdgcn_mfma_f32_16x16x32_bf16(a0, bbv, acc[0][ni], 0, 0, 0);
      acc[1][ni] = __builtin_amdgcn_mfma_f32_16x16x32_bf16(a1, bbv, acc[1][ni], 0, 0, 0);
    }
    __syncthreads();
  }

  // ---- exp in place on k accumulators ----
#pragma unroll
  for (int ni = 0; ni < 8; ++ni)
#pragma unroll
    for (int rg = 0; rg < 4; ++rg) acc[0][ni][rg] = __expf(acc[0][ni][rg]);

  // ---- k row-sums of exp -> atomic (unnormalized softmax denominators) ----
  {
    float sp[4] = {0.f, 0.f, 0.f, 0.f};
#pragma unroll
    for (int ni = 0; ni < 8; ++ni)
#pragma unroll
      for (int rg = 0; rg < 4; ++rg) sp[rg] += acc[0][ni][rg];
#pragma unroll
    for (int rg = 0; rg < 4; ++rg) {
      float s = sp[rg];
      s += __shfl_down(s, 8, 16);
      s += __shfl_down(s, 4, 16);
      s += __shfl_down(s, 2, 16);
      s += __shfl_down(s, 1, 16);
      if (l15 == 0) atomicAdd(&sums[b * 128 + wv * 16 + q * 4 + rg], s);
    }
  }
  // ---- context, two 64-row phases (LDS budget) ----
  float* cp = ctxp + ((size_t)chunk * 32 + b * 4) * 1024;
#pragma unroll
  for (int ph = 0; ph < 2; ++ph) {
    if ((wv >> 2) == ph) {
      const int r = (wv & 3) * 16 + q * 4;
#pragma unroll
      for (int ni = 0; ni < 8; ++ni)
#pragma unroll
        for (int rg = 0; rg < 4; ++rg) {
          sh.e.Lk[r + rg][ni * 16 + l15] = f2bf(acc[0][ni][rg]);   // already exp'd
          sh.e.Lv[r + rg][ni * 16 + l15] = f2bf(acc[1][ni][rg]);
        }
    }
    __syncthreads();
    const int hl = wv >> 2, nq = wv & 3;
    f32x4 c2[2][2];
    c2[0][0] = 0.f; c2[0][1] = 0.f; c2[1][0] = 0.f; c2[1][1] = 0.f;
    bfrag ka[2], vb[2];
#pragma unroll
    for (int d2 = 0; d2 < 2; ++d2)
      ka[d2] = *(const bfrag*)&sh.e.Lk[hl * 32 + d2 * 16 + l15][nq * 32 + q * 8];
#pragma unroll
    for (int e2 = 0; e2 < 2; ++e2)
      vb[e2] = *(const bfrag*)&sh.e.Lv[hl * 32 + e2 * 16 + l15][nq * 32 + q * 8];
#pragma unroll
    for (int d2 = 0; d2 < 2; ++d2)
#pragma unroll
      for (int e2 = 0; e2 < 2; ++e2)
        c2[d2][e2] = __builtin_amdgcn_mfma_f32_16x16x32_bf16(ka[d2], vb[e2], c2[d2][e2], 0, 0, 0);
    const int slot = hl * 2 + (nq & 1);
    if (nq < 2) {
#pragma unroll
      for (int d2 = 0; d2 < 2; ++d2)
#pragma unroll
        for (int e2 = 0; e2 < 2; ++e2)
#pragma unroll
          for (int rg = 0; rg < 4; ++rg)
            sh.e.Pc[slot][(d2 * 16 + q * 4 + rg) * 32 + e2 * 16 + l15] = c2[d2][e2][rg];
    }
    __syncthreads();
    if (nq >= 2) {
#pragma unroll
      for (int d2 = 0; d2 < 2; ++d2)
#pragma unroll
        for (int e2 = 0; e2 < 2; ++e2)
#pragma unroll
          for (int rg = 0; rg < 4; ++rg)
            sh.e.Pc[slot][(d2 * 16 + q * 4 + rg) * 32 + e2 * 16 + l15] += c2[d2][e2][rg];
    }
    __syncthreads();
    for (int idx = t; idx < 2048; idx += 512) {
      const int h2 = idx >> 10, pos = idx & 1023;
      cp[(ph * 2 + h2) * 1024 + pos] = sh.e.Pc[h2 * 2][pos] + sh.e.Pc[h2 * 2 + 1][pos];
    }
    __syncthreads();
  }
}

// ---------------- reduce ctx partials over 128 chunks ----------------
__global__ __launch_bounds__(256) void la_reduce(const float* __restrict__ ctxp,
                                                 float* __restrict__ ctxu) {
  const int gid = blockIdx.x * 256 + threadIdx.x;   // 0..32767
  float s = 0.f;
#pragma unroll 8
  for (int c = 0; c < 128; ++c) s += ctxp[(size_t)c * 32768 + gid];
  ctxu[gid] = s;
}

// ---------------- Weff[b][o][h*32+d] = (1/sum_d) * sum_e w_out[o][h*32+e]*ctxu[b,h,d,e] (fp32) ----------------
__global__ __launch_bounds__(128) void la_weff(const float* __restrict__ w_out,
                                               const float* __restrict__ ctxu,
                                               const float* __restrict__ sums,
                                               float* __restrict__ weffF) {
  const int o = blockIdx.x;
  const int b = blockIdx.y;
  const int cp = threadIdx.x;
  const int h = cp >> 5, d = cp & 31;
  const float* wrow = w_out + (size_t)o * HID + h * 32;
  const float* crow = ctxu + ((size_t)(b * 4 + h) * 32 + d) * 32;
  float s = 0.f;
#pragma unroll 8
  for (int e = 0; e < 32; ++e) s += wrow[e] * crow[e];
  s *= (1.0f / sums[b * 128 + h * 32 + d]);
  weffF[((size_t)b * 256 + o) * HID + cp] = s;
}

// ---------------- Wcomb[b][o][c] = sum_hd Weff[b][o][hd] * Wq[hd][c]  (Wq = w_qkv rows 0..127) ----------------
__global__ __launch_bounds__(256) void la_wcomb(const float* __restrict__ weffF,
                                                const float* __restrict__ w_qkv,
                                                unsigned short* __restrict__ wcomb) {
  __shared__ float ws[128];
  const int o = blockIdx.x;
  const int b = blockIdx.y;
  const int t = threadIdx.x;   // = c
  if (t < 128) ws[t] = weffF[((size_t)b * 256 + o) * HID + t];
  __syncthreads();
  float s = 0.f;
#pragma unroll 8
  for (int hd = 0; hd < 128; ++hd) s += ws[hd] * w_qkv[(size_t)hd * CIN + t];
  wcomb[((size_t)b * 256 + o) * 256 + t] = f2bf(s);
}

// ---------------- out[b][o][n] = sum_c Wcomb[b][o][c] * x[b][c][n] + b_out[o] ----------------
// Full M=256 per block (x read once), 512 threads = 8 waves, wave tile 64m x 64n.
// x staged via the same in-LDS transpose-convert + register prefetch as la_fused.
__global__ __launch_bounds__(512, 4) void la_out(const unsigned short* __restrict__ wcomb,
                                                 const float* __restrict__ x,
                                                 const float* __restrict__ b_out,
                                                 float* __restrict__ out) {
  __shared__ __align__(16) unsigned short At[256][40];   // 20480 B
  __shared__ __align__(16) unsigned short Bt[128][40];   // 10240 B
  const int n0 = blockIdx.x * 128;
  const int b = blockIdx.y;
  const int t = threadIdx.x;
  const int lane = t & 63, wv = t >> 6;
  const int l15 = lane & 15, q = lane >> 4;
  const int wm = (wv & 3) * 64;    // 4 m-frags of 16
  const int wn = (wv >> 2) * 64;   // 4 n-frags of 16
  const int cl = t & 31, n16 = (t >> 5) * 8;
  const float* xp = x + (size_t)b * CIN * NSP + n0;
  const unsigned short* abase = wcomb + (size_t)b * 256 * 256;
  f32x4 acc[4][4];
#pragma unroll
  for (int i = 0; i < 4; ++i)
#pragma unroll
    for (int j = 0; j < 4; ++j) acc[i][j] = 0.0f;

  float4 xa0, xa1;
  {
    const float* xr = xp + (size_t)cl * NSP + n16;
    xa0 = *(const float4*)xr;
    xa1 = *(const float4*)(xr + 4);
  }

  for (int kc = 0; kc < 8; ++kc) {
    // Bt from prefetched x regs
    Bt[n16 + 0][cl] = f2bf(xa0.x);
    Bt[n16 + 1][cl] = f2bf(xa0.y);
    Bt[n16 + 2][cl] = f2bf(xa0.z);
    Bt[n16 + 3][cl] = f2bf(xa0.w);
    Bt[n16 + 4][cl] = f2bf(xa1.x);
    Bt[n16 + 5][cl] = f2bf(xa1.y);
    Bt[n16 + 6][cl] = f2bf(xa1.z);
    Bt[n16 + 7][cl] = f2bf(xa1.w);
    // At: bf16 copy, 256x32 per kc, 2 tasks/thread (wcomb is 1 MB, L2-resident)
#pragma unroll
    for (int i = 0; i < 2; ++i) {
      const int id = t + i * 512;
      const int row = id >> 2, c8 = (id & 3) * 8;
      *(uint4*)&At[row][c8] = *(const uint4*)(abase + (size_t)row * 256 + kc * 32 + c8);
    }
    __syncthreads();
    if (kc < 7) {
      const float* xr = xp + (size_t)((kc + 1) * 32 + cl) * NSP + n16;
      xa0 = *(const float4*)xr;
      xa1 = *(const float4*)(xr + 4);
    }
    bfrag a[4];
#pragma unroll
    for (int mi = 0; mi < 4; ++mi) a[mi] = *(const bfrag*)&At[wm + mi * 16 + l15][q * 8];
#pragma unroll
    for (int ni = 0; ni < 4; ++ni) {
      bfrag bbv = *(const bfrag*)&Bt[wn + ni * 16 + l15][q * 8];
#pragma unroll
      for (int mi = 0; mi < 4; ++mi)
        acc[mi][ni] = __builtin_amdgcn_mfma_f32_16x16x32_bf16(a[mi], bbv, acc[mi][ni], 0, 0, 0);
    }
    __syncthreads();
  }
  float* obase = out + (size_t)b * 256 * NSP;
#pragma unroll
  for (int mi = 0; mi < 4; ++mi) {
    const int ob = wm + mi * 16 + q * 4;
    const float4 bias = *(const float4*)(b_out + ob);
    float ba[4] = {bias.x, bias.y, bias.z, bias.w};
#pragma unroll
    for (int ni = 0; ni < 4; ++ni) {
      const int n = n0 + wn + ni * 16 + l15;
#pragma unroll
      for (int rg = 0; rg < 4; ++rg)
        obase[(size_t)(ob + rg) * NSP + n] = acc[mi][ni][rg] + ba[rg];
    }
  }
}

// ---------------- workspace layout ----------------
// ctxp  : 0        , 16777216 B  (128 chunks * 32 bh * 1024 fp32)
// ctxu  : 16777216 , 131072 B
// sums  : 16908288 , 4096 B      (fp32, zeroed each call)
// weffF : 16912384 , 1048576 B   (fp32)
// wcomb : 17960960 , 1048576 B   (bf16)
// total ~19 MB

extern "C" void kernel_launch(void* const* d_in, const int* in_sizes, int n_in,
                              void* d_out, int out_size, void* d_ws, size_t ws_size,
                              hipStream_t stream) {
  (void)in_sizes; (void)n_in; (void)out_size; (void)ws_size;
  const float* x     = (const float*)d_in[0];
  const float* w_qkv = (const float*)d_in[1];
  const float* w_out = (const float*)d_in[2];
  const float* b_out = (const float*)d_in[3];
  float* out = (float*)d_out;
  char* ws = (char*)d_ws;
  float* ctxp          = (float*)(ws);
  float* ctxu          = (float*)(ws + 16777216);
  float* sums          = (float*)(ws + 16908288);
  float* weffF         = (float*)(ws + 16912384);
  unsigned short* wcomb = (unsigned short*)(ws + 17960960);

  hipMemsetAsync(sums, 0, 4096, stream);
  la_fused<<<dim3(NSP / 128, BB), dim3(512), 0, stream>>>(x, w_qkv, ctxp, sums);
  la_reduce<<<dim3(128), dim3(256), 0, stream>>>(ctxp, ctxu);
  la_weff<<<dim3(256, BB), dim3(128), 0, stream>>>(w_out, ctxu, sums, weffF);
  la_wcomb<<<dim3(256, BB), dim3(256), 0, stream>>>(weffF, w_qkv, wcomb);
  la_out<<<dim3(NSP / 128, BB), dim3(512), 0, stream>>>(wcomb, x, b_out, out);
}

// Round 2
// 329.297 us; speedup vs baseline: 1.0526x; 1.0526x over previous
//
#include <hip/hip_runtime.h>
#include <stdint.h>

#define BB 8
#define CIN 256
#define NSP 16384      // H*W
#define HID 128

typedef __bf16 bfrag __attribute__((ext_vector_type(8)));
typedef float  f32x4 __attribute__((ext_vector_type(4)));

__device__ __forceinline__ unsigned short f2bf(float f) {
  union { float f; unsigned int u; } v; v.f = f;
  unsigned int u = v.u;
  return (unsigned short)((u + 0x7FFFu + ((u >> 16) & 1u)) >> 16);  // RNE
}

// ---------------- prep: convert k/v weight rows to bf16 once; zero ctxu+sums ----------------
// blocks 0..63: wkvb[row][c] = bf16(w_qkv[128+row][c])  (256x256)
// block 64: zero ctxu (32768 f) + sums (1024 f) = 33792 floats contiguous
__global__ __launch_bounds__(256) void la_prep(const float* __restrict__ w_qkv,
                                               unsigned short* __restrict__ wkvb,
                                               float* __restrict__ zbase) {
  const int blk = blockIdx.x;
  const int t = threadIdx.x;
  if (blk < 64) {
    const int off = (blk * 256 + t) * 4;   // 0..65532
    const float4 wv4 = *(const float4*)(w_qkv + (size_t)128 * CIN + off);
    ushort4 p;
    p.x = f2bf(wv4.x); p.y = f2bf(wv4.y); p.z = f2bf(wv4.z); p.w = f2bf(wv4.w);
    *(ushort4*)(wkvb + off) = p;
  } else {
    // 33792 floats = 8448 float4
    for (int i = t; i < 8448; i += 256) {
      float4 z = {0.f, 0.f, 0.f, 0.f};
      *(float4*)(zbase + i * 4) = z;
    }
  }
}

// ---------------- pass 1: k/v GEMM + exp + row-sums + context -> atomic ctxu ----------------
// Block: 128-n tile of one batch, 512 threads = 8 waves.
// GEMM: M=256 (k rows 0..127, v rows 128..255 of wkvb), K=256, N=128.
// A-fragments come straight from global (wkvb bf16, L2-resident) -> no W staging.
// Xb double-buffered -> ONE barrier per kc.
__global__ __launch_bounds__(512, 4) void la_fused(const float* __restrict__ x,
                                                   const unsigned short* __restrict__ wkvb,
                                                   float* __restrict__ ctxu,
                                                   float* __restrict__ sums) {
  __shared__ __align__(16) union {
    struct { unsigned short Xb[2][128][40]; } g;                              // 20480 B
    struct { unsigned short Lk[64][136]; unsigned short Lv[64][136];
             float Pc[4][1024]; } e;                                          // 51200 B
  } sh;
  const int chunk = blockIdx.x;
  const int n0 = chunk * 128;
  const int b = blockIdx.y;
  const int t = threadIdx.x;
  const int lane = t & 63, wv = t >> 6;
  const int l15 = lane & 15, q = lane >> 4;
  const int cl = t & 31;
  const int n16 = (t >> 5) * 8;
  const float* xp = x + (size_t)b * CIN * NSP + n0;
  f32x4 acc[2][8];
#pragma unroll
  for (int i = 0; i < 2; ++i)
#pragma unroll
    for (int j = 0; j < 8; ++j) acc[i][j] = 0.0f;

  // prologue: load cols(kc=0), stage Xb[0], load cols(kc=1)
  float4 xa0, xa1;
  {
    const float* xr = xp + (size_t)cl * NSP + n16;
    xa0 = *(const float4*)xr;
    xa1 = *(const float4*)(xr + 4);
  }
  {
    sh.g.Xb[0][n16 + 0][cl] = f2bf(xa0.x);
    sh.g.Xb[0][n16 + 1][cl] = f2bf(xa0.y);
    sh.g.Xb[0][n16 + 2][cl] = f2bf(xa0.z);
    sh.g.Xb[0][n16 + 3][cl] = f2bf(xa0.w);
    sh.g.Xb[0][n16 + 4][cl] = f2bf(xa1.x);
    sh.g.Xb[0][n16 + 5][cl] = f2bf(xa1.y);
    sh.g.Xb[0][n16 + 6][cl] = f2bf(xa1.z);
    sh.g.Xb[0][n16 + 7][cl] = f2bf(xa1.w);
    const float* xr = xp + (size_t)(32 + cl) * NSP + n16;
    xa0 = *(const float4*)xr;
    xa1 = *(const float4*)(xr + 4);
  }
  __syncthreads();

#pragma unroll
  for (int kc = 0; kc < 8; ++kc) {
    const int p = kc & 1;
    // A-fragments: direct global loads from bf16 wkvb (L2-resident)
    bfrag a0 = *(const bfrag*)(wkvb + (size_t)(wv * 16 + l15) * CIN + kc * 32 + q * 8);
    bfrag a1 = *(const bfrag*)(wkvb + (size_t)(128 + wv * 16 + l15) * CIN + kc * 32 + q * 8);
    // stage next kc tile into the other buffer (regs loaded last iteration)
    if (kc < 7) {
      sh.g.Xb[p ^ 1][n16 + 0][cl] = f2bf(xa0.x);
      sh.g.Xb[p ^ 1][n16 + 1][cl] = f2bf(xa0.y);
      sh.g.Xb[p ^ 1][n16 + 2][cl] = f2bf(xa0.z);
      sh.g.Xb[p ^ 1][n16 + 3][cl] = f2bf(xa0.w);
      sh.g.Xb[p ^ 1][n16 + 4][cl] = f2bf(xa1.x);
      sh.g.Xb[p ^ 1][n16 + 5][cl] = f2bf(xa1.y);
      sh.g.Xb[p ^ 1][n16 + 6][cl] = f2bf(xa1.z);
      sh.g.Xb[p ^ 1][n16 + 7][cl] = f2bf(xa1.w);
      if (kc < 6) {
        const float* xr = xp + (size_t)((kc + 2) * 32 + cl) * NSP + n16;
        xa0 = *(const float4*)xr;
        xa1 = *(const float4*)(xr + 4);
      }
    }
#pragma unroll
    for (int ni = 0; ni < 8; ++ni) {
      bfrag bbv = *(const bfrag*)&sh.g.Xb[p][ni * 16 + l15][q * 8];
      acc[0][ni] = __builtin_amdgcn_mfma_f32_16x16x32_bf16(a0, bbv, acc[0][ni], 0, 0, 0);
      acc[1][ni] = __builtin_amdgcn_mfma_f32_16x16x32_bf16(a1, bbv, acc[1][ni], 0, 0, 0);
    }
    __syncthreads();
  }

  // ---- exp in place on k accumulators ----
#pragma unroll
  for (int ni = 0; ni < 8; ++ni)
#pragma unroll
    for (int rg = 0; rg < 4; ++rg) acc[0][ni][rg] = __expf(acc[0][ni][rg]);

  // ---- k row-sums of exp -> atomic (unnormalized softmax denominators) ----
  {
    float sp[4] = {0.f, 0.f, 0.f, 0.f};
#pragma unroll
    for (int ni = 0; ni < 8; ++ni)
#pragma unroll
      for (int rg = 0; rg < 4; ++rg) sp[rg] += acc[0][ni][rg];
#pragma unroll
    for (int rg = 0; rg < 4; ++rg) {
      float s = sp[rg];
      s += __shfl_down(s, 8, 16);
      s += __shfl_down(s, 4, 16);
      s += __shfl_down(s, 2, 16);
      s += __shfl_down(s, 1, 16);
      if (l15 == 0) atomicAdd(&sums[b * 128 + wv * 16 + q * 4 + rg], s);
    }
  }
  // ---- context, two 64-row phases (LDS budget); combine quarters in LDS, atomicAdd to ctxu ----
#pragma unroll
  for (int ph = 0; ph < 2; ++ph) {
    if ((wv >> 2) == ph) {
      const int r = (wv & 3) * 16 + q * 4;
#pragma unroll
      for (int ni = 0; ni < 8; ++ni)
#pragma unroll
        for (int rg = 0; rg < 4; ++rg) {
          sh.e.Lk[r + rg][ni * 16 + l15] = f2bf(acc[0][ni][rg]);   // already exp'd
          sh.e.Lv[r + rg][ni * 16 + l15] = f2bf(acc[1][ni][rg]);
        }
    }
    __syncthreads();
    const int hl = wv >> 2, nq = wv & 3;
    f32x4 c2[2][2];
    c2[0][0] = 0.f; c2[0][1] = 0.f; c2[1][0] = 0.f; c2[1][1] = 0.f;
    bfrag ka[2], vb[2];
#pragma unroll
    for (int d2 = 0; d2 < 2; ++d2)
      ka[d2] = *(const bfrag*)&sh.e.Lk[hl * 32 + d2 * 16 + l15][nq * 32 + q * 8];
#pragma unroll
    for (int e2 = 0; e2 < 2; ++e2)
      vb[e2] = *(const bfrag*)&sh.e.Lv[hl * 32 + e2 * 16 + l15][nq * 32 + q * 8];
#pragma unroll
    for (int d2 = 0; d2 < 2; ++d2)
#pragma unroll
      for (int e2 = 0; e2 < 2; ++e2)
        c2[d2][e2] = __builtin_amdgcn_mfma_f32_16x16x32_bf16(ka[d2], vb[e2], c2[d2][e2], 0, 0, 0);
    const int slot = hl * 2 + (nq & 1);
    if (nq < 2) {
#pragma unroll
      for (int d2 = 0; d2 < 2; ++d2)
#pragma unroll
        for (int e2 = 0; e2 < 2; ++e2)
#pragma unroll
          for (int rg = 0; rg < 4; ++rg)
            sh.e.Pc[slot][(d2 * 16 + q * 4 + rg) * 32 + e2 * 16 + l15] = c2[d2][e2][rg];
    }
    __syncthreads();
    if (nq >= 2) {
#pragma unroll
      for (int d2 = 0; d2 < 2; ++d2)
#pragma unroll
        for (int e2 = 0; e2 < 2; ++e2)
#pragma unroll
          for (int rg = 0; rg < 4; ++rg)
            sh.e.Pc[slot][(d2 * 16 + q * 4 + rg) * 32 + e2 * 16 + l15] += c2[d2][e2][rg];
    }
    __syncthreads();
    for (int idx = t; idx < 2048; idx += 512) {
      const int h2 = idx >> 10, pos = idx & 1023;
      atomicAdd(&ctxu[(size_t)b * 4096 + (ph * 2 + h2) * 1024 + pos],
                sh.e.Pc[h2 * 2][pos] + sh.e.Pc[h2 * 2 + 1][pos]);
    }
    __syncthreads();
  }
}

// ---------------- mid: weff row (in LDS) -> wcomb row, fused ----------------
// block = (o, b), 256 threads.
// phase1 (t<128): weff[o][t] = (1/sums[t]) * sum_e w_out[o][h*32+e]*ctxu[b,h,d,e]
// phase2 (all):   wcomb[b][o][c] = bf16( sum_hd weff[o][hd] * Wq[hd][c] )
__global__ __launch_bounds__(256) void la_mid(const float* __restrict__ w_out,
                                              const float* __restrict__ ctxu,
                                              const float* __restrict__ sums,
                                              const float* __restrict__ w_qkv,
                                              unsigned short* __restrict__ wcomb) {
  __shared__ float wrow[128];
  const int o = blockIdx.x;
  const int b = blockIdx.y;
  const int t = threadIdx.x;
  if (t < 128) {
    const int h = t >> 5, d = t & 31;
    const float* wr = w_out + (size_t)o * HID + h * 32;
    const float* cr = ctxu + ((size_t)(b * 4 + h) * 32 + d) * 32;
    float s = 0.f;
#pragma unroll 8
    for (int e = 0; e < 32; ++e) s += wr[e] * cr[e];
    wrow[t] = s * (1.0f / sums[b * 128 + t]);
  }
  __syncthreads();
  float s = 0.f;
#pragma unroll 8
  for (int hd = 0; hd < 128; ++hd) s += wrow[hd] * w_qkv[(size_t)hd * CIN + t];
  wcomb[((size_t)b * 256 + o) * 256 + t] = f2bf(s);
}

// ---------------- out[b][o][n] = sum_c Wcomb[b][o][c] * x[b][c][n] + b_out[o] ----------------
// M=256 per block, N=128, 512 threads = 8 waves (64m x 64n each).
// A-fragments direct from global wcomb (bf16, L2-resident); Bt double-buffered -> 1 barrier/kc.
__global__ __launch_bounds__(512, 4) void la_out(const unsigned short* __restrict__ wcomb,
                                                 const float* __restrict__ x,
                                                 const float* __restrict__ b_out,
                                                 float* __restrict__ out) {
  __shared__ __align__(16) unsigned short Bt[2][128][40];   // 20480 B
  const int n0 = blockIdx.x * 128;
  const int b = blockIdx.y;
  const int t = threadIdx.x;
  const int lane = t & 63, wv = t >> 6;
  const int l15 = lane & 15, q = lane >> 4;
  const int wm = (wv & 3) * 64;
  const int wn = (wv >> 2) * 64;
  const int cl = t & 31, n16 = (t >> 5) * 8;
  const float* xp = x + (size_t)b * CIN * NSP + n0;
  const unsigned short* abase = wcomb + (size_t)b * 256 * 256;
  f32x4 acc[4][4];
#pragma unroll
  for (int i = 0; i < 4; ++i)
#pragma unroll
    for (int j = 0; j < 4; ++j) acc[i][j] = 0.0f;

  float4 xa0, xa1;
  {
    const float* xr = xp + (size_t)cl * NSP + n16;
    xa0 = *(const float4*)xr;
    xa1 = *(const float4*)(xr + 4);
  }
  {
    Bt[0][n16 + 0][cl] = f2bf(xa0.x);
    Bt[0][n16 + 1][cl] = f2bf(xa0.y);
    Bt[0][n16 + 2][cl] = f2bf(xa0.z);
    Bt[0][n16 + 3][cl] = f2bf(xa0.w);
    Bt[0][n16 + 4][cl] = f2bf(xa1.x);
    Bt[0][n16 + 5][cl] = f2bf(xa1.y);
    Bt[0][n16 + 6][cl] = f2bf(xa1.z);
    Bt[0][n16 + 7][cl] = f2bf(xa1.w);
    const float* xr = xp + (size_t)(32 + cl) * NSP + n16;
    xa0 = *(const float4*)xr;
    xa1 = *(const float4*)(xr + 4);
  }
  __syncthreads();

#pragma unroll
  for (int kc = 0; kc < 8; ++kc) {
    const int p = kc & 1;
    bfrag a[4];
#pragma unroll
    for (int mi = 0; mi < 4; ++mi)
      a[mi] = *(const bfrag*)(abase + (size_t)(wm + mi * 16 + l15) * 256 + kc * 32 + q * 8);
    if (kc < 7) {
      Bt[p ^ 1][n16 + 0][cl] = f2bf(xa0.x);
      Bt[p ^ 1][n16 + 1][cl] = f2bf(xa0.y);
      Bt[p ^ 1][n16 + 2][cl] = f2bf(xa0.z);
      Bt[p ^ 1][n16 + 3][cl] = f2bf(xa0.w);
      Bt[p ^ 1][n16 + 4][cl] = f2bf(xa1.x);
      Bt[p ^ 1][n16 + 5][cl] = f2bf(xa1.y);
      Bt[p ^ 1][n16 + 6][cl] = f2bf(xa1.z);
      Bt[p ^ 1][n16 + 7][cl] = f2bf(xa1.w);
      if (kc < 6) {
        const float* xr = xp + (size_t)((kc + 2) * 32 + cl) * NSP + n16;
        xa0 = *(const float4*)xr;
        xa1 = *(const float4*)(xr + 4);
      }
    }
#pragma unroll
    for (int ni = 0; ni < 4; ++ni) {
      bfrag bbv = *(const bfrag*)&Bt[p][wn + ni * 16 + l15][q * 8];
#pragma unroll
      for (int mi = 0; mi < 4; ++mi)
        acc[mi][ni] = __builtin_amdgcn_mfma_f32_16x16x32_bf16(a[mi], bbv, acc[mi][ni], 0, 0, 0);
    }
    __syncthreads();
  }
  float* obase = out + (size_t)b * 256 * NSP;
#pragma unroll
  for (int mi = 0; mi < 4; ++mi) {
    const int ob = wm + mi * 16 + q * 4;
    const float4 bias = *(const float4*)(b_out + ob);
    float ba[4] = {bias.x, bias.y, bias.z, bias.w};
#pragma unroll
    for (int ni = 0; ni < 4; ++ni) {
      const int n = n0 + wn + ni * 16 + l15;
#pragma unroll
      for (int rg = 0; rg < 4; ++rg)
        obase[(size_t)(ob + rg) * NSP + n] = acc[mi][ni][rg] + ba[rg];
    }
  }
}

// ---------------- workspace layout ----------------
// wkvb  : 0        , 131072 B   (256x256 bf16 k/v weights)
// ctxu  : 131072   , 131072 B   (fp32, zeroed by la_prep)
// sums  : 262144   , 4096 B     (fp32, zeroed by la_prep; contiguous with ctxu)
// wcomb : 266240   , 1048576 B  (bf16)
// total ~1.3 MB

extern "C" void kernel_launch(void* const* d_in, const int* in_sizes, int n_in,
                              void* d_out, int out_size, void* d_ws, size_t ws_size,
                              hipStream_t stream) {
  (void)in_sizes; (void)n_in; (void)out_size; (void)ws_size;
  const float* x     = (const float*)d_in[0];
  const float* w_qkv = (const float*)d_in[1];
  const float* w_out = (const float*)d_in[2];
  const float* b_out = (const float*)d_in[3];
  float* out = (float*)d_out;
  char* ws = (char*)d_ws;
  unsigned short* wkvb  = (unsigned short*)(ws);
  float* ctxu           = (float*)(ws + 131072);
  float* sums           = (float*)(ws + 262144);
  unsigned short* wcomb = (unsigned short*)(ws + 266240);

  la_prep<<<dim3(65), dim3(256), 0, stream>>>(w_qkv, wkvb, ctxu);
  la_fused<<<dim3(NSP / 128, BB), dim3(512), 0, stream>>>(x, wkvb, ctxu, sums);
  la_mid<<<dim3(256, BB), dim3(256), 0, stream>>>(w_out, ctxu, sums, w_qkv, wcomb);
  la_out<<<dim3(NSP / 128, BB), dim3(512), 0, stream>>>(wcomb, x, b_out, out);
}